// Round 7
// baseline (422.840 us; speedup 1.0000x reference)
//
#include <hip/hip_runtime.h>
#include <hip/hip_bf16.h>

typedef __hip_bfloat16 bf16;
typedef unsigned short u16;
typedef __attribute__((ext_vector_type(8))) short short8;
typedef __attribute__((ext_vector_type(4))) float f32x4;

#define HW 4096
#define NB (64*HW)

__device__ __forceinline__ f32x4 MFMA16(short8 a, short8 b, f32x4 c){
  return __builtin_amdgcn_mfma_f32_16x16x32_bf16(a, b, c, 0, 0, 0);
}

// diagnostic fill (fp32 now)
__global__ __launch_bounds__(256) void k_const(float* __restrict__ out, float v, int n){
  int i = blockIdx.x*256 + threadIdx.x;
  if (i < n) out[i] = v;
}

// ---------------- BN fold ----------------
// bn: [0,64) invp | [64,128) biasp | [128,192) invc | [192,256) biasc | [256,768) invo | [768,1280) biaso
__global__ __launch_bounds__(512) void k_prep(
    const float* __restrict__ gp, const float* __restrict__ bp,
    const float* __restrict__ mp, const float* __restrict__ vp,
    const float* __restrict__ gc, const float* __restrict__ bc,
    const float* __restrict__ mc, const float* __restrict__ vc,
    const float* __restrict__ go, const float* __restrict__ bo,
    const float* __restrict__ mo, const float* __restrict__ vo,
    float* __restrict__ bn){
  int t = threadIdx.x;
  if (t < 64){
    float iv = gp[t] * rsqrtf(vp[t] + 1e-5f);
    bn[t] = iv; bn[64+t] = bp[t] - mp[t]*iv;
    float ic = gc[t] * rsqrtf(vc[t] + 1e-5f);
    bn[128+t] = ic; bn[192+t] = bc[t] - mc[t]*ic;
  }
  float io = go[t] * rsqrtf(vo[t] + 1e-5f);
  bn[256+t] = io; bn[768+t] = bo[t] - mo[t]*io;
}

// ---------------- conv_in, scalar ----------------
// grid (16 ptiles of 256, 16 ch-groups of 8, 4 b). y<8 -> fp (wp1), y>=8 -> fcb (wc1)
__global__ __launch_bounds__(256) void k_conv_in_s(
    const float* __restrict__ x, const float* __restrict__ wp1, const float* __restrict__ wc1,
    const float* __restrict__ bn, float* __restrict__ fp, float* __restrict__ fcb){
  const int t = threadIdx.x;
  const int y = blockIdx.y, b = blockIdx.z;
  const bool isP = y < 8;
  const int c0 = (y & 7) * 8;
  const float* w    = isP ? wp1 : wc1;
  const float* inv  = isP ? bn       : bn + 128;
  const float* bias = isP ? bn + 64  : bn + 192;
  float* outp = isP ? fp : fcb;
  const int p = blockIdx.x*256 + t;
  const float* xb = x + (size_t)b*512*HW + p;
  float acc0=0.f,acc1=0.f,acc2=0.f,acc3=0.f,acc4=0.f,acc5=0.f,acc6=0.f,acc7=0.f;
  for (int k = 0; k < 512; k++){
    float xv = xb[(size_t)k*HW];
    const float* wk = w + (size_t)c0*512 + k;
    acc0 = fmaf(wk[0*512], xv, acc0);
    acc1 = fmaf(wk[1*512], xv, acc1);
    acc2 = fmaf(wk[2*512], xv, acc2);
    acc3 = fmaf(wk[3*512], xv, acc3);
    acc4 = fmaf(wk[4*512], xv, acc4);
    acc5 = fmaf(wk[5*512], xv, acc5);
    acc6 = fmaf(wk[6*512], xv, acc6);
    acc7 = fmaf(wk[7*512], xv, acc7);
  }
  float a[8] = {acc0,acc1,acc2,acc3,acc4,acc5,acc6,acc7};
  for (int j = 0; j < 8; j++){
    int c = c0 + j;
    outp[(size_t)b*NB + (size_t)c*HW + p] = fmaf(a[j], inv[c], bias[c]);
  }
}

// ---------------- qkv, scalar ----------------
// grid (16 ptiles, 24 = 3 mats * 8 ch-groups, 4 b). Q,K transposed [p][c]; V natural [c][p].
__global__ __launch_bounds__(256) void k_qkv_s(
    const float* __restrict__ fp,
    const float* __restrict__ wb,  const float* __restrict__ bbv,
    const float* __restrict__ wc2, const float* __restrict__ bc2,
    const float* __restrict__ wd,  const float* __restrict__ bd,
    bf16* __restrict__ fB, bf16* __restrict__ fC, bf16* __restrict__ fD){
  const int t = threadIdx.x;
  const int y = blockIdx.y, mat = y >> 3, c0 = (y & 7)*8, b = blockIdx.z;
  const float* w    = (mat == 0) ? wb  : (mat == 1 ? wc2 : wd);
  const float* bias = (mat == 0) ? bbv : (mat == 1 ? bc2 : bd);
  bf16* outp        = (mat == 0) ? fB  : (mat == 1 ? fC  : fD);
  const int p = blockIdx.x*256 + t;
  const float* in = fp + (size_t)b*NB + p;
  float acc[8] = {0.f,0.f,0.f,0.f,0.f,0.f,0.f,0.f};
  for (int k = 0; k < 64; k++){
    float fv = in[(size_t)k*HW];
    for (int j = 0; j < 8; j++)
      acc[j] = fmaf(w[(size_t)(c0+j)*64 + k], fv, acc[j]);
  }
  if (mat < 2){
    bf16* ob = outp + (size_t)b*NB;
    for (int j = 0; j < 8; j++)
      ob[(size_t)p*64 + c0 + j] = __float2bfloat16(acc[j] + bias[c0+j]);
  } else {
    for (int j = 0; j < 8; j++)
      outp[(size_t)b*NB + (size_t)(c0+j)*HW + p] = __float2bfloat16(acc[j] + bias[c0+j]);
  }
}

// ---------------- channel attention: gram + softmax(-S), scalar ----------------
__global__ __launch_bounds__(64) void k_gram_s(
    const float* __restrict__ fcb, float* __restrict__ attn){
  __shared__ float rowc[4096];
  const int c = blockIdx.x, b = blockIdx.y, d = threadIdx.x;
  const float* fa = fcb + (size_t)b*NB;
  for (int i = d; i < 4096; i += 64) rowc[i] = fa[(size_t)c*HW + i];
  __syncthreads();
  const float* frow = fa + (size_t)d*HW;
  float s = 0.f;
  for (int n = 0; n < 4096; n++) s = fmaf(frow[n], rowc[n], s);
  float z = -s;
  float m = z;
  for (int off = 32; off; off >>= 1) m = fmaxf(m, __shfl_xor(m, off));
  float e = __expf(fminf(z - m, 0.f));
  float ss = e;
  for (int off = 32; off; off >>= 1) ss += __shfl_xor(ss, off);
  attn[(size_t)b*4096 + (size_t)c*64 + d] = e / ss;
}

// ---------------- position attention (two-pass MFMA flash) ----------------
__global__ __launch_bounds__(256) void k_pos_attn(
    const u16* __restrict__ fBt, const u16* __restrict__ fCt, const u16* __restrict__ fDv,
    const float* __restrict__ fpl, const float* __restrict__ alphap,
    float* __restrict__ fus){
  __shared__ __align__(16) u16 Qt[64*72];
  __shared__ __align__(16) u16 Kt[64*72];
  __shared__ __align__(16) u16 Vt[64*72];
  __shared__ __align__(16) u16 Pt[64*72];
  __shared__ float St[64*65];
  __shared__ float red2[256];
  __shared__ float mrow[64], lrow[64];

  const int t = threadIdx.x;
  const int b = blockIdx.y, q0 = blockIdx.x*64;
  const int wv = t>>6, lane = t&63, quad = lane>>4, lr = lane&15;
  const int j = t>>2, qq = t&3;
  const u16* Fb = fBt + (size_t)b*NB;
  const u16* Fc = fCt + (size_t)b*NB;
  const u16* Fd = fDv + (size_t)b*NB;

  {
    int j2 = t>>2, ch = (t&3)*16;
    *(uint4*)&Qt[j2*72 + ch]     = *(const uint4*)&Fb[(size_t)(q0+j2)*64 + ch];
    *(uint4*)&Qt[j2*72 + ch + 8] = *(const uint4*)&Fb[(size_t)(q0+j2)*64 + ch + 8];
  }

  float mpart = -3.0e38f;
  for (int k0 = 0; k0 < HW; k0 += 64){
    __syncthreads();
    { int kk = t>>2, ch = (t&3)*16;
      *(uint4*)&Kt[kk*72 + ch]     = *(const uint4*)&Fc[(size_t)(k0+kk)*64 + ch];
      *(uint4*)&Kt[kk*72 + ch + 8] = *(const uint4*)&Fc[(size_t)(k0+kk)*64 + ch + 8];
    }
    __syncthreads();
    short8 a0 = *(short8*)&Qt[(wv*16+lr)*72 + quad*8];
    short8 a1 = *(short8*)&Qt[(wv*16+lr)*72 + 32 + quad*8];
    #pragma unroll
    for (int ks = 0; ks < 4; ks++){
      short8 bf0 = *(short8*)&Kt[(ks*16+lr)*72 + quad*8];
      short8 bf1 = *(short8*)&Kt[(ks*16+lr)*72 + 32 + quad*8];
      f32x4 acc = {0.f,0.f,0.f,0.f};
      acc = MFMA16(a0, bf0, acc);
      acc = MFMA16(a1, bf1, acc);
      #pragma unroll
      for (int r = 0; r < 4; r++)
        St[(wv*16 + quad*4 + r)*65 + ks*16 + lr] = acc[r];
    }
    __syncthreads();
    #pragma unroll
    for (int i = 0; i < 16; i++) mpart = fmaxf(mpart, St[j*65 + qq*16 + i]);
  }
  __syncthreads();
  red2[t] = mpart;
  __syncthreads();
  if (qq == 0) mrow[j] = fmaxf(fmaxf(red2[t], red2[t+1]), fmaxf(red2[t+2], red2[t+3]));
  __syncthreads();
  const float mj = mrow[j];

  f32x4 accO[4];
  #pragma unroll
  for (int cs = 0; cs < 4; cs++) accO[cs] = (f32x4){0.f,0.f,0.f,0.f};
  float lpart = 0.f;
  for (int k0 = 0; k0 < HW; k0 += 64){
    __syncthreads();
    { int kk = t>>2, ch = (t&3)*16;
      *(uint4*)&Kt[kk*72 + ch]     = *(const uint4*)&Fc[(size_t)(k0+kk)*64 + ch];
      *(uint4*)&Kt[kk*72 + ch + 8] = *(const uint4*)&Fc[(size_t)(k0+kk)*64 + ch + 8];
      int c = t>>2, kc = (t&3)*16;
      *(uint4*)&Vt[c*72 + kc]     = *(const uint4*)&Fd[(size_t)c*HW + k0 + kc];
      *(uint4*)&Vt[c*72 + kc + 8] = *(const uint4*)&Fd[(size_t)c*HW + k0 + kc + 8];
    }
    __syncthreads();
    short8 a0 = *(short8*)&Qt[(wv*16+lr)*72 + quad*8];
    short8 a1 = *(short8*)&Qt[(wv*16+lr)*72 + 32 + quad*8];
    #pragma unroll
    for (int ks = 0; ks < 4; ks++){
      short8 bf0 = *(short8*)&Kt[(ks*16+lr)*72 + quad*8];
      short8 bf1 = *(short8*)&Kt[(ks*16+lr)*72 + 32 + quad*8];
      f32x4 acc = {0.f,0.f,0.f,0.f};
      acc = MFMA16(a0, bf0, acc);
      acc = MFMA16(a1, bf1, acc);
      #pragma unroll
      for (int r = 0; r < 4; r++)
        St[(wv*16 + quad*4 + r)*65 + ks*16 + lr] = acc[r];
    }
    __syncthreads();
    #pragma unroll
    for (int i = 0; i < 16; i++){
      int kk = qq*16 + i;
      float e = __expf(fminf(St[j*65 + kk] - mj, 0.f));
      bf16 h = __float2bfloat16(e);
      Pt[j*72 + kk] = *(u16*)&h;
      lpart += e;
    }
    __syncthreads();
    short8 p0 = *(short8*)&Pt[(wv*16+lr)*72 + quad*8];
    short8 p1 = *(short8*)&Pt[(wv*16+lr)*72 + 32 + quad*8];
    #pragma unroll
    for (int cs = 0; cs < 4; cs++){
      short8 v0 = *(short8*)&Vt[(cs*16+lr)*72 + quad*8];
      short8 v1 = *(short8*)&Vt[(cs*16+lr)*72 + 32 + quad*8];
      accO[cs] = MFMA16(p0, v0, accO[cs]);
      accO[cs] = MFMA16(p1, v1, accO[cs]);
    }
  }
  __syncthreads();
  red2[t] = lpart;
  __syncthreads();
  if (qq == 0) lrow[j] = red2[t] + red2[t+1] + red2[t+2] + red2[t+3];
  __syncthreads();

  const float al = alphap[0];
  const float* Fp = fpl + (size_t)b*NB;
  float* Fo = fus + (size_t)b*NB;
  #pragma unroll
  for (int r = 0; r < 4; r++){
    int qg = wv*16 + quad*4 + r;
    float rl = 1.f / fmaxf(lrow[qg], 1e-20f);
    #pragma unroll
    for (int cs = 0; cs < 4; cs++){
      int c = cs*16 + lr;
      Fo[(size_t)c*HW + q0 + qg] =
          fmaf(al, accO[cs][r]*rl, Fp[(size_t)c*HW + q0 + qg]);
    }
  }
}

// ---------------- channel apply, scalar ----------------
__global__ __launch_bounds__(256) void k_chan_apply_s(
    const float* __restrict__ fcb, const float* __restrict__ attn,
    const float* __restrict__ betap, float* __restrict__ fus){
  const int t = threadIdx.x;
  const int c0 = blockIdx.y*8, b = blockIdx.z;
  const int p = blockIdx.x*256 + t;
  const float* fa = fcb + (size_t)b*NB;
  const float* at = attn + (size_t)b*4096;
  float acc[8] = {0.f,0.f,0.f,0.f,0.f,0.f,0.f,0.f};
  for (int d = 0; d < 64; d++){
    float fv = fa[(size_t)d*HW + p];
    for (int j = 0; j < 8; j++)
      acc[j] = fmaf(at[(size_t)(c0+j)*64 + d], fv, acc[j]);
  }
  const float be = betap[0];
  for (int j = 0; j < 8; j++){
    size_t idx = (size_t)b*NB + (size_t)(c0+j)*HW + p;
    fus[idx] += fmaf(be, acc[j], fa[(size_t)(c0+j)*HW + p]);
  }
}

// ---------------- out conv, scalar, FP32 OUTPUT ----------------
__global__ __launch_bounds__(256) void k_conv_out_s(
    const float* __restrict__ fus, const float* __restrict__ wo,
    const float* __restrict__ bn, float* __restrict__ out){
  const int t = threadIdx.x;
  const int o0 = blockIdx.y*8, b = blockIdx.z;
  const int p = blockIdx.x*256 + t;
  const float* fu = fus + (size_t)b*NB + p;
  float acc[8] = {0.f,0.f,0.f,0.f,0.f,0.f,0.f,0.f};
  for (int c = 0; c < 64; c++){
    float fv = fu[(size_t)c*HW];
    for (int j = 0; j < 8; j++)
      acc[j] = fmaf(wo[(size_t)(o0+j)*64 + c], fv, acc[j]);
  }
  for (int j = 0; j < 8; j++){
    int o = o0 + j;
    out[(size_t)b*512*HW + (size_t)o*HW + p] = fmaf(acc[j], bn[256+o], bn[768+o]);
  }
}

extern "C" void kernel_launch(void* const* d_in, const int* in_sizes, int n_in,
                              void* d_out, int out_size, void* d_ws, size_t ws_size,
                              hipStream_t stream){
  static const int dictSz[24] = {8388608,32768,64,64,64,64,32768,64,64,64,64,
                                 4096,64,4096,64,4096,64,1,1,32768,512,512,512,512};
  bool n24 = (n_in == 24);
  bool dictOk = n24;
  if (n24){
    for (int i = 0; i < 24; i++) if (in_sizes[i] != dictSz[i]) dictOk = false;
  }
  bool wsOk = (ws_size >= (size_t)(19u << 20));
  float* out = (float*)d_out;

  if (!dictOk){
    k_const<<<(out_size + 255)/256, 256, 0, stream>>>(out, 32.f, out_size); return;
  }
  if (!wsOk){
    k_const<<<(out_size + 255)/256, 256, 0, stream>>>(out, 48.f, out_size); return;
  }

  const float* x    = (const float*)d_in[0];
  const float* wp1  = (const float*)d_in[1];
  const float* gp1  = (const float*)d_in[2];  const float* bp1 = (const float*)d_in[3];
  const float* mp1  = (const float*)d_in[4];  const float* vp1 = (const float*)d_in[5];
  const float* wc1  = (const float*)d_in[6];
  const float* gc1  = (const float*)d_in[7];  const float* bc1 = (const float*)d_in[8];
  const float* mc1  = (const float*)d_in[9];  const float* vc1 = (const float*)d_in[10];
  const float* wb   = (const float*)d_in[11]; const float* bb  = (const float*)d_in[12];
  const float* wc2  = (const float*)d_in[13]; const float* bc2 = (const float*)d_in[14];
  const float* wd   = (const float*)d_in[15]; const float* bd  = (const float*)d_in[16];
  const float* alp  = (const float*)d_in[17]; const float* bet = (const float*)d_in[18];
  const float* wo   = (const float*)d_in[19];
  const float* go   = (const float*)d_in[20]; const float* bo  = (const float*)d_in[21];
  const float* mo   = (const float*)d_in[22]; const float* vo  = (const float*)d_in[23];

  char* w8 = (char*)d_ws;
  float* fp    = (float*)(w8);
  float* fcb   = (float*)(w8 + (4u<<20));
  float* fus   = (float*)(w8 + (8u<<20));
  bf16*  fB    = (bf16*) (w8 + (12u<<20));   // [q][c]
  bf16*  fC    = (bf16*) (w8 + (14u<<20));   // [k][c]
  bf16*  fD    = (bf16*) (w8 + (16u<<20));   // [c][k]
  float* attnc = (float*)(w8 + (18u<<20));
  float* bn    = (float*)(w8 + (18u<<20) + 65536);

  k_prep<<<1, 512, 0, stream>>>(gp1,bp1,mp1,vp1, gc1,bc1,mc1,vc1, go,bo,mo,vo, bn);
  k_conv_in_s<<<dim3(16,16,4), 256, 0, stream>>>(x, wp1, wc1, bn, fp, fcb);
  k_qkv_s<<<dim3(16,24,4), 256, 0, stream>>>(fp, wb,bb, wc2,bc2, wd,bd, fB, fC, fD);
  k_gram_s<<<dim3(64,4), 64, 0, stream>>>(fcb, attnc);
  k_pos_attn<<<dim3(64,4), 256, 0, stream>>>((const u16*)fB, (const u16*)fC, (const u16*)fD,
                                             fp, alp, fus);
  k_chan_apply_s<<<dim3(16,8,4), 256, 0, stream>>>(fcb, attnc, bet, fus);
  k_conv_out_s<<<dim3(16,64,4), 256, 0, stream>>>(fus, wo, bn, out);
}

// Round 8
// 348.436 us; speedup vs baseline: 1.2135x; 1.2135x over previous
//
#include <hip/hip_runtime.h>
#include <hip/hip_bf16.h>

typedef __hip_bfloat16 bf16;
typedef unsigned short u16;
typedef __attribute__((ext_vector_type(8))) short short8;
typedef __attribute__((ext_vector_type(4))) float f32x4;

#define HW 4096
#define NB (64*HW)

__device__ __forceinline__ f32x4 MFMA16(short8 a, short8 b, f32x4 c){
  return __builtin_amdgcn_mfma_f32_16x16x32_bf16(a, b, c, 0, 0, 0);
}

// diagnostic fill (fp32 output)
__global__ __launch_bounds__(256) void k_const(float* __restrict__ out, float v, int n){
  int i = blockIdx.x*256 + threadIdx.x;
  if (i < n) out[i] = v;
}

// ---------------- BN fold ----------------
// bn: [0,64) invp | [64,128) biasp | [128,192) invc | [192,256) biasc | [256,768) invo | [768,1280) biaso
__global__ __launch_bounds__(512) void k_prep(
    const float* __restrict__ gp, const float* __restrict__ bp,
    const float* __restrict__ mp, const float* __restrict__ vp,
    const float* __restrict__ gc, const float* __restrict__ bc,
    const float* __restrict__ mc, const float* __restrict__ vc,
    const float* __restrict__ go, const float* __restrict__ bo,
    const float* __restrict__ mo, const float* __restrict__ vo,
    float* __restrict__ bn){
  int t = threadIdx.x;
  if (t < 64){
    float iv = gp[t] * rsqrtf(vp[t] + 1e-5f);
    bn[t] = iv; bn[64+t] = bp[t] - mp[t]*iv;
    float ic = gc[t] * rsqrtf(vc[t] + 1e-5f);
    bn[128+t] = ic; bn[192+t] = bc[t] - mc[t]*ic;
  }
  float io = go[t] * rsqrtf(vo[t] + 1e-5f);
  bn[256+t] = io; bn[768+t] = bo[t] - mo[t]*io;
}

// ---------------- conv_in: 512->64 x2, BN folded, LDS weights ----------------
// grid (16 ptiles of 256 px, 8 cgroups, 4 b); cg<4 -> fp(wp1), cg>=4 -> fcb(wc1)
__global__ __launch_bounds__(256) void k_conv_in(
    const float* __restrict__ x, const float* __restrict__ wp1, const float* __restrict__ wc1,
    const float* __restrict__ bn, float* __restrict__ fp, float* __restrict__ fcb){
  __shared__ __align__(16) float Wl[512][16];
  const int t = threadIdx.x;
  const int cg = blockIdx.y, b = blockIdx.z;
  const bool isP = cg < 4;
  const int c0 = (cg & 3) * 16;
  const float* w = isP ? wp1 : wc1;
  const float* inv  = isP ? bn       : bn + 128;
  const float* bias = isP ? bn + 64  : bn + 192;
  float* outp = isP ? fp : fcb;
  for (int i = t; i < 8192; i += 256){
    int c = i & 15, k = i >> 4;
    Wl[k][c] = w[(size_t)(c0 + c)*512 + k];
  }
  __syncthreads();
  const int p = blockIdx.x*256 + t;
  const float* xb = x + (size_t)b*512*HW + p;
  float acc[16];
  #pragma unroll
  for (int i = 0; i < 16; i++) acc[i] = 0.f;
  for (int k = 0; k < 512; k++){
    float xv = xb[(size_t)k*HW];
    float4 w0 = *(const float4*)&Wl[k][0];
    float4 w1 = *(const float4*)&Wl[k][4];
    float4 w2 = *(const float4*)&Wl[k][8];
    float4 w3 = *(const float4*)&Wl[k][12];
    acc[0]=fmaf(w0.x,xv,acc[0]); acc[1]=fmaf(w0.y,xv,acc[1]); acc[2]=fmaf(w0.z,xv,acc[2]); acc[3]=fmaf(w0.w,xv,acc[3]);
    acc[4]=fmaf(w1.x,xv,acc[4]); acc[5]=fmaf(w1.y,xv,acc[5]); acc[6]=fmaf(w1.z,xv,acc[6]); acc[7]=fmaf(w1.w,xv,acc[7]);
    acc[8]=fmaf(w2.x,xv,acc[8]); acc[9]=fmaf(w2.y,xv,acc[9]); acc[10]=fmaf(w2.z,xv,acc[10]); acc[11]=fmaf(w2.w,xv,acc[11]);
    acc[12]=fmaf(w3.x,xv,acc[12]); acc[13]=fmaf(w3.y,xv,acc[13]); acc[14]=fmaf(w3.z,xv,acc[14]); acc[15]=fmaf(w3.w,xv,acc[15]);
  }
  const size_t base = (size_t)b*NB + p;
  #pragma unroll
  for (int i = 0; i < 16; i++){
    int c = c0 + i;
    outp[base + (size_t)c*HW] = fmaf(acc[i], inv[c], bias[c]);
  }
}

// ---------------- QKV convs; Q,K transposed [p][c], V natural [c][p] ----------------
// grid (8 ptiles of 512, 12 = 3 mats * 4 cgroups, 4 b)
__global__ __launch_bounds__(256) void k_qkv(
    const float* __restrict__ fp,
    const float* __restrict__ wb,  const float* __restrict__ bbv,
    const float* __restrict__ wc2, const float* __restrict__ bc2,
    const float* __restrict__ wd,  const float* __restrict__ bd,
    bf16* __restrict__ fB, bf16* __restrict__ fC, bf16* __restrict__ fD){
  __shared__ __align__(16) float Wl[64][16];
  __shared__ float Bl[16];
  const int t = threadIdx.x;
  const int mg = blockIdx.y, mat = mg >> 2, c0 = (mg & 3)*16, b = blockIdx.z;
  const float* w    = (mat == 0) ? wb  : (mat == 1 ? wc2 : wd);
  const float* bias = (mat == 0) ? bbv : (mat == 1 ? bc2 : bd);
  bf16* outp        = (mat == 0) ? fB  : (mat == 1 ? fC  : fD);
  for (int i = t; i < 1024; i += 256){
    int c = i & 15, k = i >> 4;
    Wl[k][c] = w[(size_t)(c0 + c)*64 + k];
  }
  if (t < 16) Bl[t] = bias[c0 + t];
  __syncthreads();
  const int p = blockIdx.x*512 + t*2;
  const float* in = fp + (size_t)b*NB + p;
  float2 acc[16];
  #pragma unroll
  for (int i = 0; i < 16; i++){ acc[i].x = 0.f; acc[i].y = 0.f; }
  for (int k = 0; k < 64; k++){
    float2 xv = *(const float2*)(in + (size_t)k*HW);
    float4 w0 = *(const float4*)&Wl[k][0];
    float4 w1 = *(const float4*)&Wl[k][4];
    float4 w2 = *(const float4*)&Wl[k][8];
    float4 w3 = *(const float4*)&Wl[k][12];
    float wv[16] = {w0.x,w0.y,w0.z,w0.w, w1.x,w1.y,w1.z,w1.w,
                    w2.x,w2.y,w2.z,w2.w, w3.x,w3.y,w3.z,w3.w};
    #pragma unroll
    for (int i = 0; i < 16; i++){
      acc[i].x = fmaf(wv[i], xv.x, acc[i].x);
      acc[i].y = fmaf(wv[i], xv.y, acc[i].y);
    }
  }
  if (mat < 2){
    bf16* ob = outp + (size_t)b*NB;
    #pragma unroll
    for (int i = 0; i < 16; i += 2){
      __hip_bfloat162 h0 = __float22bfloat162_rn(
          make_float2(acc[i].x + Bl[i], acc[i+1].x + Bl[i+1]));
      __hip_bfloat162 h1 = __float22bfloat162_rn(
          make_float2(acc[i].y + Bl[i], acc[i+1].y + Bl[i+1]));
      *(__hip_bfloat162*)&ob[(size_t)p*64 + c0 + i]     = h0;
      *(__hip_bfloat162*)&ob[(size_t)(p+1)*64 + c0 + i] = h1;
    }
  } else {
    const size_t base = (size_t)b*NB + p;
    #pragma unroll
    for (int i = 0; i < 16; i++){
      float bl = Bl[i];
      __hip_bfloat162 o2 = __float22bfloat162_rn(make_float2(acc[i].x + bl, acc[i].y + bl));
      *(__hip_bfloat162*)&outp[base + (size_t)(c0 + i)*HW] = o2;
    }
  }
}

// ---------------- channel attention: gram row + softmax(-S) ----------------
// grid (64 c, 4 b), 256 threads
__global__ __launch_bounds__(256) void k_chan_attn(
    const float* __restrict__ fcb, float* __restrict__ attn){
  __shared__ __align__(16) float rowc[4096];
  __shared__ float red[256];
  __shared__ float Srow[64];
  const int c = blockIdx.x, b = blockIdx.y, t = threadIdx.x;
  const float* fa = fcb + (size_t)b*NB;
  #pragma unroll
  for (int i = 0; i < 4; i++){
    int n = i*1024 + t*4;
    *(float4*)&rowc[n] = *(const float4*)&fa[(size_t)c*HW + n];
  }
  __syncthreads();
  const int d = t >> 2, part = t & 3;
  const float* frow = fa + (size_t)d*HW + part*1024;
  const float* rc = rowc + part*1024;
  float s = 0.f;
  for (int i = 0; i < 1024; i += 4){
    float4 xv = *(const float4*)&frow[i];
    float4 rv = *(const float4*)&rc[i];
    s += xv.x*rv.x + xv.y*rv.y + xv.z*rv.z + xv.w*rv.w;
  }
  red[t] = s;
  __syncthreads();
  if (part == 0) Srow[d] = red[t] + red[t+1] + red[t+2] + red[t+3];
  __syncthreads();
  if (t < 64){
    float z = -Srow[t];
    float m = z;
    #pragma unroll
    for (int off = 32; off; off >>= 1) m = fmaxf(m, __shfl_xor(m, off));
    float e = __expf(fminf(z - m, 0.f));
    float ss = e;
    #pragma unroll
    for (int off = 32; off; off >>= 1) ss += __shfl_xor(ss, off);
    attn[(size_t)b*4096 + (size_t)c*64 + t] = e / ss;
  }
}

// ---------------- position attention: ONE-PASS online-softmax MFMA flash ----------------
// fBt [q][c], fCt [k][c], fDv [c][k] (bf16). fusion = alpha*PV/l + fp.
// 64 q per block; K-tile 128; softmax state (m,l,alpha) in registers per lane
// (C/D rows quad*4+reg are identical for the S-tile and O-accumulator).
__global__ __launch_bounds__(256) void k_pos_attn(
    const u16* __restrict__ fBt, const u16* __restrict__ fCt, const u16* __restrict__ fDv,
    const float* __restrict__ fpl, const float* __restrict__ alphap,
    float* __restrict__ fus){
  __shared__ __align__(16) u16 Kt[128*72];   // [k][c] pitch 72
  __shared__ __align__(16) u16 Vt[64*136];   // [c][k] pitch 136
  __shared__ __align__(16) u16 Pt[64*136];   // [q][k] pitch 136

  const int t = threadIdx.x;
  const int b = blockIdx.y, q0 = blockIdx.x*64;
  const int wv = t>>6, lane = t&63, quad = lane>>4, lr = lane&15;
  const u16* Fb = fBt + (size_t)b*NB;
  const u16* Fc = fCt + (size_t)b*NB;
  const u16* Fd = fDv + (size_t)b*NB;

  // Q A-fragments straight from global ([q][c] layout): row = q0 + wv*16 + lr
  const size_t qoff = (size_t)(q0 + wv*16 + lr)*64;
  short8 a0 = *(const short8*)&Fb[qoff + quad*8];
  short8 a1 = *(const short8*)&Fb[qoff + 32 + quad*8];

  float m[4] = {-3.0e38f,-3.0e38f,-3.0e38f,-3.0e38f};
  float l[4] = {0.f,0.f,0.f,0.f};
  f32x4 accO[4];
  #pragma unroll
  for (int cs = 0; cs < 4; cs++) accO[cs] = (f32x4){0.f,0.f,0.f,0.f};

  // staging indices
  const int skk = t>>1, sch = (t&1)*32;        // Kt: 128 rows x 64 ch
  const int svc = t>>2, svk = (t&3)*32;        // Vt: 64 rows x 128 keys

  for (int k0 = 0; k0 < HW; k0 += 128){
    __syncthreads();   // prev PV consumed Kt/Vt/Pt
    {
      const u16* ks = &Fc[(size_t)(k0+skk)*64 + sch];
      u16* kd = &Kt[skk*72 + sch];
      ((uint4*)kd)[0] = ((const uint4*)ks)[0];
      ((uint4*)kd)[1] = ((const uint4*)ks)[1];
      ((uint4*)kd)[2] = ((const uint4*)ks)[2];
      ((uint4*)kd)[3] = ((const uint4*)ks)[3];
      const u16* vs = &Fd[(size_t)svc*HW + k0 + svk];
      u16* vd = &Vt[svc*136 + svk];
      ((uint4*)vd)[0] = ((const uint4*)vs)[0];
      ((uint4*)vd)[1] = ((const uint4*)vs)[1];
      ((uint4*)vd)[2] = ((const uint4*)vs)[2];
      ((uint4*)vd)[3] = ((const uint4*)vs)[3];
    }
    __syncthreads();

    // S = Q K^T over 128 keys: 8 key-subtiles of 16
    f32x4 s[8];
    #pragma unroll
    for (int ks = 0; ks < 8; ks++){
      short8 b0 = *(short8*)&Kt[(ks*16+lr)*72 + quad*8];
      short8 b1 = *(short8*)&Kt[(ks*16+lr)*72 + 32 + quad*8];
      f32x4 acc = {0.f,0.f,0.f,0.f};
      acc = MFMA16(a0, b0, acc);
      acc = MFMA16(a1, b1, acc);
      s[ks] = acc;
    }

    // online softmax in registers; rows r are q = q0 + wv*16 + quad*4 + r
    float mx[4];
    #pragma unroll
    for (int r = 0; r < 4; r++){
      float v = s[0][r];
      #pragma unroll
      for (int ks = 1; ks < 8; ks++) v = fmaxf(v, s[ks][r]);
      mx[r] = v;
    }
    #pragma unroll
    for (int off = 1; off < 16; off <<= 1){
      #pragma unroll
      for (int r = 0; r < 4; r++) mx[r] = fmaxf(mx[r], __shfl_xor(mx[r], off));
    }
    float al[4], rs[4];
    #pragma unroll
    for (int r = 0; r < 4; r++){
      float mn = fmaxf(m[r], mx[r]);
      al[r] = __expf(m[r] - mn);
      m[r] = mn;
      rs[r] = 0.f;
    }
    #pragma unroll
    for (int ks = 0; ks < 8; ks++){
      #pragma unroll
      for (int r = 0; r < 4; r++){
        float e = __expf(s[ks][r] - m[r]);   // arg <= 0 by construction
        rs[r] += e;
        bf16 h = __float2bfloat16(e);
        Pt[(wv*16 + quad*4 + r)*136 + ks*16 + lr] = *(u16*)&h;
      }
    }
    #pragma unroll
    for (int off = 1; off < 16; off <<= 1){
      #pragma unroll
      for (int r = 0; r < 4; r++) rs[r] += __shfl_xor(rs[r], off);
    }
    #pragma unroll
    for (int r = 0; r < 4; r++) l[r] = l[r]*al[r] + rs[r];
    #pragma unroll
    for (int cs = 0; cs < 4; cs++){
      #pragma unroll
      for (int r = 0; r < 4; r++) accO[cs][r] *= al[r];
    }
    __syncthreads();   // Pt visible

    // O += P V : A = P[16q x 128k], B = V[c][k]
    #pragma unroll
    for (int kc = 0; kc < 4; kc++){
      short8 pf = *(short8*)&Pt[(wv*16+lr)*136 + kc*32 + quad*8];
      #pragma unroll
      for (int cs = 0; cs < 4; cs++){
        short8 vf = *(short8*)&Vt[(cs*16+lr)*136 + kc*32 + quad*8];
        accO[cs] = MFMA16(pf, vf, accO[cs]);
      }
    }
  }

  // epilogue: fus = alpha * O/l + fp
  const float alp = alphap[0];
  const float* Fp = fpl + (size_t)b*NB;
  float* Fo = fus + (size_t)b*NB;
  #pragma unroll
  for (int r = 0; r < 4; r++){
    int qg = q0 + wv*16 + quad*4 + r;
    float rl = 1.f / fmaxf(l[r], 1e-20f);
    #pragma unroll
    for (int cs = 0; cs < 4; cs++){
      int c = cs*16 + lr;
      Fo[(size_t)c*HW + qg] = fmaf(alp, accO[cs][r]*rl, Fp[(size_t)c*HW + qg]);
    }
  }
}

// ---------------- channel apply: fus += beta*(attn@fa) + fcb ----------------
// grid (16 ptiles of 256, 8 cgroups of 8, 4 b)
__global__ __launch_bounds__(256) void k_chan_apply(
    const float* __restrict__ fcb, const float* __restrict__ attn,
    const float* __restrict__ betap, float* __restrict__ fus){
  __shared__ __align__(16) float Ar2[64][8];
  const int t = threadIdx.x;
  const int c0 = blockIdx.y*8, b = blockIdx.z;
  for (int i = t; i < 512; i += 256){
    int d = i >> 3, ci = i & 7;
    Ar2[d][ci] = attn[(size_t)b*4096 + (size_t)(c0 + ci)*64 + d];
  }
  __syncthreads();
  const int p = blockIdx.x*256 + t;
  const float* fa = fcb + (size_t)b*NB;
  float acc[8] = {0.f,0.f,0.f,0.f,0.f,0.f,0.f,0.f};
  for (int d = 0; d < 64; d++){
    float v = fa[(size_t)d*HW + p];
    float4 A0 = *(const float4*)&Ar2[d][0];
    float4 A1 = *(const float4*)&Ar2[d][4];
    acc[0]=fmaf(A0.x,v,acc[0]); acc[1]=fmaf(A0.y,v,acc[1]); acc[2]=fmaf(A0.z,v,acc[2]); acc[3]=fmaf(A0.w,v,acc[3]);
    acc[4]=fmaf(A1.x,v,acc[4]); acc[5]=fmaf(A1.y,v,acc[5]); acc[6]=fmaf(A1.z,v,acc[6]); acc[7]=fmaf(A1.w,v,acc[7]);
  }
  const float be = betap[0];
  #pragma unroll
  for (int i = 0; i < 8; i++){
    size_t idx = (size_t)b*NB + (size_t)(c0 + i)*HW + p;
    fus[idx] += fmaf(be, acc[i], fa[(size_t)(c0 + i)*HW + p]);
  }
}

// ---------------- out conv (64 -> 512) + BN, fp32 out, LDS weights ----------------
// grid (8 ptiles of 512, 32 ogroups of 16, 4 b)
__global__ __launch_bounds__(256) void k_conv_out(
    const float* __restrict__ fus, const float* __restrict__ wo,
    const float* __restrict__ bn, float* __restrict__ out){
  __shared__ __align__(16) float Wl[64][16];
  const int t = threadIdx.x;
  const int o0 = blockIdx.y*16, b = blockIdx.z;
  for (int i = t; i < 1024; i += 256){
    int o = i & 15, c = i >> 4;
    Wl[c][o] = wo[(size_t)(o0 + o)*64 + c];
  }
  __syncthreads();
  const int p = blockIdx.x*512 + t*2;
  const float* fu = fus + (size_t)b*NB + p;
  float2 acc[16];
  #pragma unroll
  for (int i = 0; i < 16; i++){ acc[i].x = 0.f; acc[i].y = 0.f; }
  for (int c = 0; c < 64; c++){
    float2 xv = *(const float2*)(fu + (size_t)c*HW);
    float4 w0 = *(const float4*)&Wl[c][0];
    float4 w1 = *(const float4*)&Wl[c][4];
    float4 w2 = *(const float4*)&Wl[c][8];
    float4 w3 = *(const float4*)&Wl[c][12];
    float wv[16] = {w0.x,w0.y,w0.z,w0.w, w1.x,w1.y,w1.z,w1.w,
                    w2.x,w2.y,w2.z,w2.w, w3.x,w3.y,w3.z,w3.w};
    #pragma unroll
    for (int i = 0; i < 16; i++){
      acc[i].x = fmaf(wv[i], xv.x, acc[i].x);
      acc[i].y = fmaf(wv[i], xv.y, acc[i].y);
    }
  }
  #pragma unroll
  for (int i = 0; i < 16; i++){
    int o = o0 + i;
    float iv = bn[256+o], bs = bn[768+o];
    float* op = &out[(size_t)b*512*HW + (size_t)o*HW + p];
    op[0] = fmaf(acc[i].x, iv, bs);
    op[1] = fmaf(acc[i].y, iv, bs);
  }
}

extern "C" void kernel_launch(void* const* d_in, const int* in_sizes, int n_in,
                              void* d_out, int out_size, void* d_ws, size_t ws_size,
                              hipStream_t stream){
  static const int dictSz[24] = {8388608,32768,64,64,64,64,32768,64,64,64,64,
                                 4096,64,4096,64,4096,64,1,1,32768,512,512,512,512};
  bool dictOk = (n_in == 24);
  if (dictOk){
    for (int i = 0; i < 24; i++) if (in_sizes[i] != dictSz[i]) dictOk = false;
  }
  bool wsOk = (ws_size >= (size_t)(19u << 20));
  float* out = (float*)d_out;
  if (!dictOk){ k_const<<<(out_size+255)/256, 256, 0, stream>>>(out, 32.f, out_size); return; }
  if (!wsOk)  { k_const<<<(out_size+255)/256, 256, 0, stream>>>(out, 48.f, out_size); return; }

  const float* x    = (const float*)d_in[0];
  const float* wp1  = (const float*)d_in[1];
  const float* gp1  = (const float*)d_in[2];  const float* bp1 = (const float*)d_in[3];
  const float* mp1  = (const float*)d_in[4];  const float* vp1 = (const float*)d_in[5];
  const float* wc1  = (const float*)d_in[6];
  const float* gc1  = (const float*)d_in[7];  const float* bc1 = (const float*)d_in[8];
  const float* mc1  = (const float*)d_in[9];  const float* vc1 = (const float*)d_in[10];
  const float* wb   = (const float*)d_in[11]; const float* bb  = (const float*)d_in[12];
  const float* wc2  = (const float*)d_in[13]; const float* bc2 = (const float*)d_in[14];
  const float* wd   = (const float*)d_in[15]; const float* bd  = (const float*)d_in[16];
  const float* alp  = (const float*)d_in[17]; const float* bet = (const float*)d_in[18];
  const float* wo   = (const float*)d_in[19];
  const float* go   = (const float*)d_in[20]; const float* bo  = (const float*)d_in[21];
  const float* mo   = (const float*)d_in[22]; const float* vo  = (const float*)d_in[23];

  char* w8 = (char*)d_ws;
  float* fp    = (float*)(w8);
  float* fcb   = (float*)(w8 + (4u<<20));
  float* fus   = (float*)(w8 + (8u<<20));
  bf16*  fB    = (bf16*) (w8 + (12u<<20));   // [q][c]
  bf16*  fC    = (bf16*) (w8 + (14u<<20));   // [k][c]
  bf16*  fD    = (bf16*) (w8 + (16u<<20));   // [c][k]
  float* attnc = (float*)(w8 + (18u<<20));
  float* bn    = (float*)(w8 + (18u<<20) + 65536);

  k_prep<<<1, 512, 0, stream>>>(gp1,bp1,mp1,vp1, gc1,bc1,mc1,vc1, go,bo,mo,vo, bn);
  k_conv_in<<<dim3(16,8,4), 256, 0, stream>>>(x, wp1, wc1, bn, fp, fcb);
  k_qkv<<<dim3(8,12,4), 256, 0, stream>>>(fp, wb,bb, wc2,bc2, wd,bd, fB, fC, fD);
  k_chan_attn<<<dim3(64,4), 256, 0, stream>>>(fcb, attnc);
  k_pos_attn<<<dim3(64,4), 256, 0, stream>>>((const u16*)fB, (const u16*)fC, (const u16*)fD,
                                             fp, alp, fus);
  k_chan_apply<<<dim3(16,8,4), 256, 0, stream>>>(fcb, attnc, bet, fus);
  k_conv_out<<<dim3(8,32,4), 256, 0, stream>>>(fus, wo, bn, out);
}